// Round 5
// baseline (493.167 us; speedup 1.0000x reference)
//
#include <hip/hip_runtime.h>
#include <hip/hip_bf16.h>
#include <math.h>

typedef float f32x4 __attribute__((ext_vector_type(4)));
using bf16x8 = __attribute__((ext_vector_type(8))) short;
using f32x16 = __attribute__((ext_vector_type(16))) float;
typedef unsigned short ushortT;
using u16x4 = __attribute__((ext_vector_type(4))) unsigned short;

__device__ __forceinline__ ushortT f2bf(float f) {
  unsigned int u = __builtin_bit_cast(unsigned int, f);
  u = (u + 0x7FFFu + ((u >> 16) & 1u)) >> 16;
  return (ushortT)u;
}
__device__ __forceinline__ float bf2f(ushortT u) {
  return __builtin_bit_cast(float, (unsigned int)u << 16);
}

// emb tiled layout: emb_t[(row>>5)*128*256 + kc*256 + (row&31)*8 + j]
//   where flat k = kc*8 + j  (kc = 0..127, k = 0..1023)

// ---------------------------------------------------------------------------
// Prepack (coalesced reads): bf16 MFMA fragment layouts + u = cls_W @ out_W.
// Bp1 [nt=2][l][j]        = w1[tap=(l>>4)*8+j][ch=nt*16+(l&15)]
// Bp2 [s*2+nt][l][j]      = w2[k][co]  k=s*16+hi*8+j, co=nt*32+l31
// BpA [nt][s][l][j]       = W [k][col] k=s*16+hi*8+j, col=nt*32+l31
// ---------------------------------------------------------------------------
__global__ __launch_bounds__(256) void prepack_kernel(
    const float* __restrict__ w1, const float* __restrict__ w2,
    const float* __restrict__ aW1, const float* __restrict__ aW2,
    const float* __restrict__ aW3, const float* __restrict__ cls_W,
    const float* __restrict__ out_W, ushortT* __restrict__ Bp1,
    ushortT* __restrict__ Bp2, ushortT* __restrict__ BpA1,
    ushortT* __restrict__ BpA2, ushortT* __restrict__ BpA3,
    float* __restrict__ u) {
  const int i = blockIdx.x * 256 + threadIdx.x;
  const int n1 = 1024, n2 = 51200, nA = 262144, nU = 65536;
  if (i < n1) {
    int nt = i >> 9, l = (i >> 3) & 63, j = i & 7;
    int tap = ((l >> 4) << 3) + j, ch = nt * 16 + (l & 15);
    Bp1[i] = (tap < 25) ? f2bf(w1[tap * 32 + ch]) : (ushortT)0;
  } else if (i < n1 + n2) {
    int t = i - n1;
    int co = t & 63, k = t >> 6;  // coalesced read over co
    int s = k >> 4, hi = (k >> 3) & 1, j = k & 7;
    int nt = co >> 5, l31 = co & 31;
    Bp2[(s * 2 + nt) * 512 + (hi * 32 + l31) * 8 + j] = f2bf(w2[k * 64 + co]);
  } else if (i < n1 + n2 + 3 * nA) {
    int t = i - n1 - n2;
    int m = t >> 18, r = t & (nA - 1);
    const float* aW = (m == 0) ? aW1 : ((m == 1) ? aW2 : aW3);
    ushortT* dst = (m == 0) ? BpA1 : ((m == 1) ? BpA2 : BpA3);
    int col = r & 255, k = r >> 8;  // coalesced read over col
    int nt = col >> 5, l31 = col & 31;
    int s = k >> 4, hi = (k >> 3) & 1, j = k & 7;
    dst[nt * 32768 + s * 512 + (hi * 32 + l31) * 8 + j] =
        f2bf(aW[k * 256 + col]);
  } else if (i < n1 + n2 + 3 * nA + nU) {
    int t = i - (n1 + n2 + 3 * nA);
    int k = t >> 6, lane = t & 63;
    float p = 0.f;
#pragma unroll
    for (int j = 0; j < 8; ++j) {
      int jj = lane + j * 64;
      p += cls_W[k * 512 + jj] * out_W[jj];
    }
#pragma unroll
    for (int off = 32; off; off >>= 1) p += __shfl_xor(p, off, 64);
    if (lane == 0) u[k] = p;
  }
}

// ---------------------------------------------------------------------------
// Fused conv: 4 instances/block, one wave per instance, barrier-free until
// the cooperative epilogue. conv2 B read directly from L2 (no LDS staging).
// ---------------------------------------------------------------------------
#define PADW 36
__global__ __launch_bounds__(256, 3) void fused_conv_mfma_kernel(
    const float* __restrict__ x, const ushortT* __restrict__ Bp1,
    const float* __restrict__ b1g, const ushortT* __restrict__ Bp2,
    const float* __restrict__ b2g, ushortT* __restrict__ emb1) {
  __shared__ ushortT h1s[4][144 * PADW];          // 41472 B
  __shared__ __align__(16) char uni[4 * 2080];    // xs (1568B) / epi (2048B)

  const int tid = threadIdx.x, wv = tid >> 6, lane = tid & 63;
  const int inst = blockIdx.x * 4 + wv;
  ushortT* xs = (ushortT*)(uni + wv * 2080);
  ushortT* h1w = &h1s[wv][0];

  // x -> bf16 LDS (wave-private, no barrier)
  {
    const float* xg = x + (size_t)inst * 784;
#pragma unroll
    for (int t = 0; t < 4; ++t) {
      int g = lane + t * 64;
      if (g < 196) {
        f32x4 v = *(const f32x4*)&xg[g * 4];
        u16x4 o;
#pragma unroll
        for (int z = 0; z < 4; ++z) o[z] = f2bf(v[z]);
        *(u16x4*)&xs[g * 4] = o;
      }
    }
  }

  // ---------------- conv1 via MFMA 16x16x32 (wave-private) ----------------
  {
    const int arow = lane & 15, kg = lane >> 4;
    int koff[8], kval[8];
#pragma unroll
    for (int j = 0; j < 8; ++j) {
      int tap = kg * 8 + j;
      int ky = (tap * 13) >> 6;
      int kx = tap - ky * 5;
      kval[j] = (tap < 25);
      koff[j] = kval[j] ? (ky * 28 + kx) : 0;
    }
    bf16x8 w1f0 = *(const bf16x8*)&Bp1[lane * 8];
    bf16x8 w1f1 = *(const bf16x8*)&Bp1[(64 + lane) * 8];
    const float bA = b1g[arow], bB = b1g[16 + arow];

#pragma unroll 4
    for (int g = 0; g < 36; ++g) {
      int R = g * 16 + arow;
      int q = R >> 2, quad = R & 3;
      int qy = q / 12, qx = q - qy * 12;
      int base = (2 * qy + (quad >> 1)) * 28 + 2 * qx + (quad & 1);
      bf16x8 a;
#pragma unroll
      for (int j = 0; j < 8; ++j) {
        ushortT vv = xs[base + koff[j]];
        a[j] = (short)(kval[j] ? vv : (ushortT)0);
      }
      f32x4 c0, c1;
#pragma unroll
      for (int z = 0; z < 4; ++z) { c0[z] = 0.f; c1[z] = 0.f; }
      c0 = __builtin_amdgcn_mfma_f32_16x16x32_bf16(a, w1f0, c0, 0, 0, 0);
      c1 = __builtin_amdgcn_mfma_f32_16x16x32_bf16(a, w1f1, c1, 0, 0, 0);
      int qo = g * 4 + kg;
      float m0 = fmaxf(fmaxf(c0[0], c0[1]), fmaxf(c0[2], c0[3]));
      float m1 = fmaxf(fmaxf(c1[0], c1[1]), fmaxf(c1[2], c1[3]));
      h1w[qo * PADW + arow] = f2bf(fmaxf(m0 + bA, 0.f));
      h1w[qo * PADW + 16 + arow] = f2bf(fmaxf(m1 + bB, 0.f));
    }
  }
  // wave-private h1; compiler inserts lgkmcnt waits — no barrier needed

  // ---------------- conv2 via MFMA 32x32x16 (B from L2) -------------------
  {
    const int hi = lane >> 5, l31 = lane & 31;
    int rowbase0, rowbase1;
    {
      int q2 = l31 >> 2, quad2 = l31 & 3;
      rowbase0 = (2 * (q2 >> 2) + (quad2 >> 1)) * 12 + 2 * (q2 & 3) + (quad2 & 1);
      q2 = (32 + l31) >> 2;
      rowbase1 = (2 * (q2 >> 2) + (quad2 >> 1)) * 12 + 2 * (q2 & 3) + (quad2 & 1);
    }
    const int ab0 = rowbase0 * PADW + hi * 8;
    const int ab1 = rowbase1 * PADW + hi * 8;
    const ushortT* bglane = Bp2 + lane * 8;

    f32x16 a00, a01, a10, a11;
#pragma unroll
    for (int z = 0; z < 16; ++z) { a00[z] = 0.f; a01[z] = 0.f; a10[z] = 0.f; a11[z] = 0.f; }

#pragma unroll
    for (int s = 0; s < 50; ++s) {
      const int tap = s >> 1;
      const int ky = tap / 5, kx = tap - (tap / 5) * 5;
      const int aoff = (ky * 12 + kx) * PADW + ((s & 1) << 4);
      bf16x8 bf0 = *(const bf16x8*)&bglane[(s * 2 + 0) * 512];
      bf16x8 bf1 = *(const bf16x8*)&bglane[(s * 2 + 1) * 512];
      bf16x8 af0 = *(const bf16x8*)&h1w[ab0 + aoff];
      bf16x8 af1 = *(const bf16x8*)&h1w[ab1 + aoff];
      a00 = __builtin_amdgcn_mfma_f32_32x32x16_bf16(af0, bf0, a00, 0, 0, 0);
      a01 = __builtin_amdgcn_mfma_f32_32x32x16_bf16(af0, bf1, a01, 0, 0, 0);
      a10 = __builtin_amdgcn_mfma_f32_32x32x16_bf16(af1, bf0, a10, 0, 0, 0);
      a11 = __builtin_amdgcn_mfma_f32_32x32x16_bf16(af1, bf1, a11, 0, 0, 0);
    }

    // epilogue: bias + pool + relu -> wave-private epi slab (flat k = p*64+c)
    ushortT* epi = (ushortT*)(uni + wv * 2080);
    const float b2_0 = b2g[l31], b2_1 = b2g[32 + l31];
#pragma unroll
    for (int rg = 0; rg < 4; ++rg) {
      float m00 = fmaxf(fmaxf(a00[rg * 4], a00[rg * 4 + 1]),
                        fmaxf(a00[rg * 4 + 2], a00[rg * 4 + 3]));
      float m01 = fmaxf(fmaxf(a01[rg * 4], a01[rg * 4 + 1]),
                        fmaxf(a01[rg * 4 + 2], a01[rg * 4 + 3]));
      float m10 = fmaxf(fmaxf(a10[rg * 4], a10[rg * 4 + 1]),
                        fmaxf(a10[rg * 4 + 2], a10[rg * 4 + 3]));
      float m11 = fmaxf(fmaxf(a11[rg * 4], a11[rg * 4 + 1]),
                        fmaxf(a11[rg * 4 + 2], a11[rg * 4 + 3]));
      int p0 = 2 * rg + hi, p1 = 8 + 2 * rg + hi;
      epi[p0 * 64 + l31] = f2bf(fmaxf(m00 + b2_0, 0.f));
      epi[p0 * 64 + 32 + l31] = f2bf(fmaxf(m01 + b2_1, 0.f));
      epi[p1 * 64 + l31] = f2bf(fmaxf(m10 + b2_0, 0.f));
      epi[p1 * 64 + 32 + l31] = f2bf(fmaxf(m11 + b2_1, 0.f));
    }
  }
  __syncthreads();

  // cooperative tiled store: emb_t[tile][kc][row&31][8], 64B-aligned lines
  {
    const int bid = blockIdx.x;
    ushortT* dstbase = emb1 + (size_t)(bid >> 3) * 32768;
    const int instoff = 4 * (bid & 7);
#pragma unroll
    for (int z = 0; z < 2; ++z) {
      int kchunk = (tid >> 2) + z * 64;
      int i = tid & 3;
      bf16x8 vv = *(const bf16x8*)(uni + i * 2080 + kchunk * 16);
      *(bf16x8*)&dstbase[(size_t)kchunk * 256 + (instoff + i) * 8] = vv;
    }
  }
}

// ---------------------------------------------------------------------------
// Attention score (all levels): s[i]=sigmoid(tanh(emb[i,:]@W+b)@v+vb).
// 64 rows/block, 8 waves = 8 N-tiles. emb in tiled layout -> coalesced A.
// ---------------------------------------------------------------------------
__global__ __launch_bounds__(512) void att_mfma_kernel(
    const ushortT* __restrict__ emb, const ushortT* __restrict__ Bp,
    const float* __restrict__ bias, const float* __restrict__ v,
    const float* __restrict__ vb, float* __restrict__ s_out) {
  __shared__ float part[64][8];
  const int tid = threadIdx.x, wv = tid >> 6, lane = tid & 63;
  const int hi = lane >> 5, l31 = lane & 31;
  const int row0 = blockIdx.x * 64;

  const ushortT* ap0 = emb + (size_t)(row0 >> 5) * 32768 + hi * 256 + l31 * 8;
  const ushortT* ap1 = ap0 + 32768;
  const ushortT* bp = Bp + ((size_t)wv * 64 * 64 + lane) * 8;

  f32x16 acc0, acc1;
#pragma unroll
  for (int z = 0; z < 16; ++z) { acc0[z] = 0.f; acc1[z] = 0.f; }

#pragma unroll 8
  for (int s = 0; s < 64; ++s) {
    bf16x8 bfr = *(const bf16x8*)(bp + s * 512);
    bf16x8 af0 = *(const bf16x8*)(ap0 + s * 512);
    bf16x8 af1 = *(const bf16x8*)(ap1 + s * 512);
    acc0 = __builtin_amdgcn_mfma_f32_32x32x16_bf16(af0, bfr, acc0, 0, 0, 0);
    acc1 = __builtin_amdgcn_mfma_f32_32x32x16_bf16(af1, bfr, acc1, 0, 0, 0);
  }

  const int col = wv * 32 + l31;
  const float bc = bias[col], vc = v[col];
#pragma unroll
  for (int r = 0; r < 16; ++r) {
    float p = tanhf(acc0[r] + bc) * vc;
#pragma unroll
    for (int off = 16; off >= 1; off >>= 1) p += __shfl_xor(p, off, 64);
    if (l31 == 0) part[(r & 3) + 8 * (r >> 2) + 4 * hi][wv] = p;
  }
#pragma unroll
  for (int r = 0; r < 16; ++r) {
    float p = tanhf(acc1[r] + bc) * vc;
#pragma unroll
    for (int off = 16; off >= 1; off >>= 1) p += __shfl_xor(p, off, 64);
    if (l31 == 0) part[32 + (r & 3) + 8 * (r >> 2) + 4 * hi][wv] = p;
  }
  __syncthreads();
  if (tid < 64) {
    float ssum = vb[0];
#pragma unroll
    for (int w = 0; w < 8; ++w) ssum += part[tid][w];
    s_out[row0 + tid] = 1.f / (1.f + expf(-ssum));
  }
}

// red[0] = max(s), red[1] = sum(exp(s - max))
__global__ __launch_bounds__(1024) void softmax_reduce_kernel(
    const float* __restrict__ s, int M, float* __restrict__ red) {
  __shared__ float sm[16], ss[16];
  const int tid = threadIdx.x;
  float mx = -INFINITY;
  for (int i = tid; i < M; i += 1024) mx = fmaxf(mx, s[i]);
#pragma unroll
  for (int off = 32; off; off >>= 1) mx = fmaxf(mx, __shfl_xor(mx, off, 64));
  if ((tid & 63) == 0) sm[tid >> 6] = mx;
  __syncthreads();
  float gmax = sm[0];
#pragma unroll
  for (int w = 1; w < 16; ++w) gmax = fmaxf(gmax, sm[w]);
  float sum = 0.f;
  for (int i = tid; i < M; i += 1024) sum += expf(s[i] - gmax);
#pragma unroll
  for (int off = 32; off; off >>= 1) sum += __shfl_xor(sum, off, 64);
  if ((tid & 63) == 0) ss[tid >> 6] = sum;
  __syncthreads();
  if (tid == 0) {
    float t = 0.f;
#pragma unroll
    for (int w = 0; w < 16; ++w) t += ss[w];
    red[0] = gmax;
    red[1] = t;
  }
}

// emb_out[b,:] = sum_{k<16} softmax_w[b*16+k] * emb_in[b*16+k,:]  (tiled IO)
__global__ __launch_bounds__(256) void segsum16_kernel(
    const ushortT* __restrict__ emb_in, const float* __restrict__ s,
    const float* __restrict__ red, ushortT* __restrict__ emb_out) {
  __shared__ float wsh[16];
  const int b = blockIdx.x, tid = threadIdx.x;
  if (tid < 16) wsh[tid] = expf(s[b * 16 + tid] - red[0]) / red[1];
  __syncthreads();
  const int kc = tid >> 1, jj = (tid & 1) * 4;
  const ushortT* src =
      emb_in + (size_t)(b >> 1) * 32768 + kc * 256 + ((b & 1) * 16) * 8 + jj;
  f32x4 acc;
#pragma unroll
  for (int z = 0; z < 4; ++z) acc[z] = 0.f;
#pragma unroll
  for (int k = 0; k < 16; ++k) {
    u16x4 uu = *(const u16x4*)(src + k * 8);
    float w = wsh[k];
    acc[0] += bf2f(uu[0]) * w;
    acc[1] += bf2f(uu[1]) * w;
    acc[2] += bf2f(uu[2]) * w;
    acc[3] += bf2f(uu[3]) * w;
  }
  u16x4 o;
#pragma unroll
  for (int z = 0; z < 4; ++z) o[z] = f2bf(acc[z]);
  *(u16x4*)(emb_out + (size_t)(b >> 5) * 32768 + kc * 256 + (b & 31) * 8 + jj) =
      o;
}

// out = sigmoid( (w3@emb3)·u + cls_b·out_W + out_b )   (emb3 tiled)
__global__ __launch_bounds__(1024) void final_kernel(
    const ushortT* __restrict__ emb3, const float* __restrict__ s3,
    const float* __restrict__ red3, const float* __restrict__ u,
    const float* __restrict__ cls_b, const float* __restrict__ out_W,
    const float* __restrict__ out_b, float* __restrict__ out) {
  __shared__ float w3[64];
  __shared__ float redp[16];
  const int tid = threadIdx.x;
  if (tid < 64) w3[tid] = expf(s3[tid] - red3[0]) / red3[1];
  __syncthreads();
  const int kc = tid >> 3, j = tid & 7;
  float outer = 0.f;
#pragma unroll
  for (int b = 0; b < 64; ++b)
    outer += w3[b] *
             bf2f(emb3[(size_t)(b >> 5) * 32768 + kc * 256 + (b & 31) * 8 + j]);
  float val = outer * u[tid] + ((tid < 512) ? cls_b[tid] * out_W[tid] : 0.f);
#pragma unroll
  for (int off = 32; off; off >>= 1) val += __shfl_xor(val, off, 64);
  if ((tid & 63) == 0) redp[tid >> 6] = val;
  __syncthreads();
  if (tid == 0) {
    float z = out_b[0];
#pragma unroll
    for (int w = 0; w < 16; ++w) z += redp[w];
    out[0] = 1.f / (1.f + expf(-z));
  }
}

// ---------------------------------------------------------------------------
extern "C" void kernel_launch(void* const* d_in, const int* in_sizes, int n_in,
                              void* d_out, int out_size, void* d_ws,
                              size_t ws_size, hipStream_t stream) {
  const float* x       = (const float*)d_in[0];
  const float* conv1_w = (const float*)d_in[1];
  const float* conv1_b = (const float*)d_in[2];
  const float* conv2_w = (const float*)d_in[3];
  const float* conv2_b = (const float*)d_in[4];
  const float* att1_W  = (const float*)d_in[5];
  const float* att1_b  = (const float*)d_in[6];
  const float* att1_v  = (const float*)d_in[7];
  const float* att1_vb = (const float*)d_in[8];
  const float* att2_W  = (const float*)d_in[9];
  const float* att2_b  = (const float*)d_in[10];
  const float* att2_v  = (const float*)d_in[11];
  const float* att2_vb = (const float*)d_in[12];
  const float* att3_W  = (const float*)d_in[13];
  const float* att3_b  = (const float*)d_in[14];
  const float* att3_v  = (const float*)d_in[15];
  const float* att3_vb = (const float*)d_in[16];
  const float* cls_W   = (const float*)d_in[17];
  const float* cls_b   = (const float*)d_in[18];
  const float* out_W   = (const float*)d_in[19];
  const float* out_b   = (const float*)d_in[20];

  char* p = (char*)d_ws;
  ushortT* emb1 = (ushortT*)p; p += (size_t)16384 * 1024 * 2;
  ushortT* Bp1  = (ushortT*)p; p += 2048;
  ushortT* Bp2  = (ushortT*)p; p += 102400;
  ushortT* BpA1 = (ushortT*)p; p += 524288;
  ushortT* BpA2 = (ushortT*)p; p += 524288;
  ushortT* BpA3 = (ushortT*)p; p += 524288;
  float* u      = (float*)p;   p += 4096;
  ushortT* emb2 = (ushortT*)p; p += (size_t)1024 * 1024 * 2;
  ushortT* emb3 = (ushortT*)p; p += 64 * 1024 * 2;
  float* s1     = (float*)p;   p += 16384 * 4;
  float* s2     = (float*)p;   p += 4096;
  float* s3     = (float*)p;   p += 256;
  float* red1   = (float*)p;   p += 256;
  float* red2   = (float*)p;   p += 256;
  float* red3   = (float*)p;   p += 256;

  prepack_kernel<<<3532, 256, 0, stream>>>(conv1_w, conv2_w, att1_W, att2_W,
                                           att3_W, cls_W, out_W, Bp1, Bp2,
                                           BpA1, BpA2, BpA3, u);
  fused_conv_mfma_kernel<<<4096, 256, 0, stream>>>(x, Bp1, conv1_b, Bp2,
                                                   conv2_b, emb1);
  att_mfma_kernel<<<256, 512, 0, stream>>>(emb1, BpA1, att1_b, att1_v, att1_vb,
                                           s1);
  softmax_reduce_kernel<<<1, 1024, 0, stream>>>(s1, 16384, red1);
  segsum16_kernel<<<1024, 256, 0, stream>>>(emb1, s1, red1, emb2);
  att_mfma_kernel<<<16, 512, 0, stream>>>(emb2, BpA2, att2_b, att2_v, att2_vb,
                                          s2);
  softmax_reduce_kernel<<<1, 1024, 0, stream>>>(s2, 1024, red2);
  segsum16_kernel<<<64, 256, 0, stream>>>(emb2, s2, red2, emb3);
  att_mfma_kernel<<<1, 512, 0, stream>>>(emb3, BpA3, att3_b, att3_v, att3_vb,
                                         s3);
  softmax_reduce_kernel<<<1, 1024, 0, stream>>>(s3, 64, red3);
  final_kernel<<<1, 1024, 0, stream>>>(emb3, s3, red3, u, cls_b, out_W, out_b,
                                       (float*)d_out);
}